// Round 15
// baseline (356.032 us; speedup 1.0000x reference)
//
#include <hip/hip_runtime.h>

// MoE forward, MI355X. fp32 router/dispatch (exact top-k), bf16 MFMA grouped
// GEMMs (9 groups = 8 experts + shared), fp32-atomic scatter-combine.
// R14: intra-step overlap test at UNCHANGED residency. GEMM: BK=32 double-
// buffered, stage(t+1) -> compute(t) -> ONE __syncthreads per step. LDS
// 33.8KB keeps 4 blocks/CU (R9 lesson: never raise waves/EU past 4; R11/R12
// lesson: keep separate small kernels). Same total barrier count as R8
// (32x1 vs 16x2) but DMA drain now overlaps a full compute phase. BK=32
// stage/read swizzle = R5-verified mapping (passed, 0 bank conflicts).

#define NTOK 8192
#define DDIM 1024
#define HDIM 1408
#define CAP  2560
#define NROWS (NTOK + 8*CAP)   // 28672 GEMM rows: [0,8192) shared, then 8*2560 expert slots
#define YN   8388608           // NTOK*DDIM

typedef __bf16 bf16x8 __attribute__((ext_vector_type(8)));
typedef float  f32x4  __attribute__((ext_vector_type(4)));

typedef __attribute__((address_space(1))) void gvoid_t;
typedef __attribute__((address_space(3))) void svoid_t;

static __device__ __forceinline__ void load_lds16(const void* g, void* l) {
  // 16B per lane, LDS dest = wave-uniform base + lane*16 (linear)
  __builtin_amdgcn_global_load_lds((gvoid_t*)g, (svoid_t*)l, 16, 0, 0);
}

// ---------------- zero y ----------------
__global__ __launch_bounds__(256) void zero_kernel(float* __restrict__ y) {
  size_t idx = (size_t)blockIdx.x * 256 + threadIdx.x;
  float4 z = make_float4(0.f, 0.f, 0.f, 0.f);
  float4* p = (float4*)y;
#pragma unroll
  for (int j = 0; j < 4; ++j) p[idx + (size_t)j * 524288] = z;
}

// ------- transpose+convert v2: in[R][C] f32 -> out[C][R] bf16, 64x32 tile, bf16x8 stores -------
// z in [0,8]: z<8 -> expert slice of (in,out); z==8 -> (in_s,out_s) shared.
__global__ __launch_bounds__(256) void tconv2_kernel(
    const float* __restrict__ in, __bf16* __restrict__ out,
    const float* __restrict__ in_s, __bf16* __restrict__ out_s, int R, int C) {
  __shared__ float t[64][33];
  int z = blockIdx.z, tid = threadIdx.x;
  const float* ip = (z < 8) ? in + (size_t)z * R * C : in_s;
  __bf16* op = (z < 8) ? out + (size_t)z * R * C : out_s;
  int c0 = blockIdx.x * 32, r0 = blockIdx.y * 64;
  int tx = tid & 31, ty = tid >> 5;          // read: 8 rows/pass, 128B/row coalesced
#pragma unroll
  for (int k = 0; k < 8; ++k)
    t[ty + k * 8][tx] = ip[(size_t)(r0 + ty + k * 8) * C + c0 + tx];
  __syncthreads();
  int cl = tid >> 3, rq = (tid & 7) * 8;     // write: one bf16x8 (16B) per thread
  bf16x8 o;                                  // LDS bank = (8q+j+p)%32 -> 2-way (free)
#pragma unroll
  for (int j = 0; j < 8; ++j) o[j] = (__bf16)t[rq + j][cl];
  *(bf16x8*)(op + (size_t)(c0 + cl) * R + r0 + rq) = o;
}

// ------- router (+ fused x->bf16 convert): fp32 logits, softmax, top-2, renorm -------
__global__ __launch_bounds__(256) void router_kernel(
    const float* __restrict__ x, const float* __restrict__ rw,
    __bf16* __restrict__ xbf,
    int2* __restrict__ e01, float2* __restrict__ p01,
    int* __restrict__ tok_row, float* __restrict__ scale_row,
    float* __restrict__ psum_part, int* __restrict__ fcnt_part) {
  __shared__ float rwl[8 * 1024];
  __shared__ float ps[8];
  __shared__ int fc[8];
  int tid = threadIdx.x;
  if (tid < 8) { ps[tid] = 0.f; fc[tid] = 0; }
  float4* rl4 = (float4*)rwl;
  const float4* rg4 = (const float4*)rw;
#pragma unroll
  for (int j = 0; j < 8; ++j) rl4[tid + 256 * j] = rg4[tid + 256 * j];
  __syncthreads();
  int lane = tid & 63, wid = tid >> 6;
  for (int it = 0; it < 8; ++it) {
    int t = blockIdx.x * 32 + wid * 8 + it;
    const float4* xt = (const float4*)(x + (size_t)t * DDIM);
    float a[8];
#pragma unroll
    for (int e = 0; e < 8; ++e) a[e] = 0.f;
    float4 v[4];
#pragma unroll
    for (int jj = 0; jj < 4; ++jj) {
      v[jj] = xt[lane * 4 + jj];
#pragma unroll
      for (int e = 0; e < 8; ++e) {
        float4 w = rl4[e * 256 + lane * 4 + jj];
        a[e] += v[jj].x * w.x + v[jj].y * w.y + v[jj].z * w.z + v[jj].w * w.w;
      }
    }
    {
      bf16x8 o0, o1;
#pragma unroll
      for (int jj = 0; jj < 2; ++jj) {
        o0[jj * 4 + 0] = (__bf16)v[jj].x; o0[jj * 4 + 1] = (__bf16)v[jj].y;
        o0[jj * 4 + 2] = (__bf16)v[jj].z; o0[jj * 4 + 3] = (__bf16)v[jj].w;
        o1[jj * 4 + 0] = (__bf16)v[jj + 2].x; o1[jj * 4 + 1] = (__bf16)v[jj + 2].y;
        o1[jj * 4 + 2] = (__bf16)v[jj + 2].z; o1[jj * 4 + 3] = (__bf16)v[jj + 2].w;
      }
      __bf16* xo = xbf + (size_t)t * DDIM + lane * 16;
      *(bf16x8*)xo = o0;
      *(bf16x8*)(xo + 8) = o1;
    }
#pragma unroll
    for (int off = 32; off >= 1; off >>= 1)
#pragma unroll
      for (int e = 0; e < 8; ++e) a[e] += __shfl_xor(a[e], off);
    if (lane == 0) {
      int am = 0; float m = a[0];
      for (int e = 1; e < 8; ++e) if (a[e] > m) { m = a[e]; am = e; }
      float s = 0.f, ex[8];
      for (int e = 0; e < 8; ++e) { ex[e] = expf(a[e] - m); s += ex[e]; }
      float inv = 1.f / s;
      int am2 = -1; float m2 = -3.4e38f;
      for (int e = 0; e < 8; ++e) if (e != am && a[e] > m2) { m2 = a[e]; am2 = e; }
      float p0 = ex[am] * inv, p1 = ex[am2] * inv;
      float rn = 1.f / (p0 + p1 + 1e-9f);
      e01[t] = make_int2(am, am2);
      p01[t] = make_float2(p0 * rn, p1 * rn);
      tok_row[t] = t;            // shared-group rows: identity gather, weight 1
      scale_row[t] = 1.f;
      atomicAdd(&fc[am], 1);
      for (int e = 0; e < 8; ++e) atomicAdd(&ps[e], ex[e] * inv);
    }
  }
  __syncthreads();
  if (tid < 8) { psum_part[blockIdx.x * 8 + tid] = ps[tid]; fcnt_part[blockIdx.x * 8 + tid] = fc[tid]; }
}

// ------- dispatch (+stat reduce +aux): stable rank within expert, capacity drop -------
__global__ __launch_bounds__(256) void dispatch_kernel(
    const int2* __restrict__ e01, const float2* __restrict__ p01,
    int* __restrict__ tok_row, float* __restrict__ scale_row, int* __restrict__ counts,
    const float* __restrict__ psum_part, const int* __restrict__ fcnt_part,
    float* __restrict__ aux_out) {
  __shared__ int lcnt[256][8];
  __shared__ float aps[8];
  __shared__ int afc[8];
  int tid = threadIdx.x;
  if (tid < 8) {
    float s = 0.f; int c = 0;
    for (int i = 0; i < 256; ++i) { s += psum_part[i * 8 + tid]; c += fcnt_part[i * 8 + tid]; }
    aps[tid] = s; afc[tid] = c;
  }
  int my[8];
#pragma unroll
  for (int e = 0; e < 8; ++e) my[e] = 0;
  int base = tid * 64;  // 256 threads * 64 entries = 16384 = N*K, contiguous => stable
  for (int j = 0; j < 64; ++j) {
    int ent = base + j; int t = ent >> 1;
    int2 ee = e01[t];
    int ex = (ent & 1) ? ee.y : ee.x;
    my[ex]++;
  }
#pragma unroll
  for (int e = 0; e < 8; ++e) lcnt[tid][e] = my[e];
  __syncthreads();
  if (tid < 8) {
    int run = 0;
    for (int i = 0; i < 256; ++i) { int c = lcnt[i][tid]; lcnt[i][tid] = run; run += c; }
    counts[tid] = run < CAP ? run : CAP;
  }
  __syncthreads();
  int offs[8];
#pragma unroll
  for (int e = 0; e < 8; ++e) offs[e] = lcnt[tid][e];
  for (int j = 0; j < 64; ++j) {
    int ent = base + j; int t = ent >> 1; int k = ent & 1;
    int2 ee = e01[t];
    int ex = k ? ee.y : ee.x;
    float pr = k ? p01[t].y : p01[t].x;
    int pos = offs[ex]++;
    if (pos < CAP) {
      int row = NTOK + ex * CAP + pos;
      tok_row[row] = t;
      scale_row[row] = pr;
    }
  }
  if (tid == 0) {
    float s = 0.f;
    for (int e = 0; e < 8; ++e) s += ((float)afc[e] / 8192.f) * (aps[e] / 8192.f);
    *aux_out = 0.08f * s;  // AUX_COEF * E = 0.01 * 8
  }
}

// ---------------- grouped GEMM, 128x128 tile, BK=32, 4 waves, DOUBLE-buffer stage-ahead ----------------
// Per step t: issue stage(t+1) into buf (t+1)&1, compute buf t&1 (8
// ds_read_b128 + 16 MFMA per wave), ONE __syncthreads (compiler emits
// vmcnt(0)+lgkmcnt(0) -> stage t+1 landed AND this step's ds_reads drained,
// so next step's stage may overwrite buf t&1: WAR-safe). DMA latency of
// stage(t+1) overlaps compute(t) intra-block, plus 4 blocks/CU cross-block.
// LDS: Sm[2][(128+128)*32]b = 32KB + 1KB tok/scl -> still 4 blocks/CU.
// BK=32 swizzle (R5-verified): stage instr j covers 16 rows x 64B; lane ->
// row j*16+(lane>>2), chunk lane&3, src chunk = chunk^((row>>1)&3); read
// chunk = (lane>>4)^((row>>1)&3). One 16x16x32 MFMA consumes full BK.
// EPI==1: H = bf16(relu(acc)^2)   EPI==2: atomicAdd(y[tok][col], acc*scale)
template <int KD, int NDT, bool GATHER, int EPI>
__global__ __launch_bounds__(256, 4) void gemm_kernel(
    const __bf16* __restrict__ A, const __bf16* __restrict__ B,
    __bf16* __restrict__ Hout, float* __restrict__ Yout,
    const int* __restrict__ counts, const int* __restrict__ tok_row,
    const float* __restrict__ scale_row) {
  constexpr int NCT = NDT / 128;
  constexpr int T = KD / 32;       // 32 (GEMM1) or 44 (GEMM2) K-steps
  constexpr int SH = NTOK / 128;   // 64 shared row-tiles
  constexpr int ET = CAP / 128;    // 20 expert row-tiles (worst case)
  // XCD bijective remap + 4-rt chunks (nwg%8==0, nwg%(4*NCT)==0 hold)
  int nwg = gridDim.x;
  int lin = (blockIdx.x & 7) * (nwg >> 3) + (blockIdx.x >> 3);
  int rem = lin % (4 * NCT);
  int rt = (lin / (4 * NCT)) * 4 + (rem & 3);
  int ct = rem >> 2;

  int g, i0, rowbase;
  if (rt < SH) { g = 8; rowbase = 0; i0 = rt << 7; }
  else { int r = rt - SH; g = r / ET; i0 = (r % ET) << 7; rowbase = NTOK + g * CAP; }
  int cnt = (g == 8) ? NTOK : counts[g];
  if (i0 >= cnt) return;  // uniform early-exit

  // Sm[buf]: A rows [0,128) then B rows [128,256), 32 k-elems (64B) per row
  __shared__ __align__(16) __bf16 Sm[2][256 * 32];   // 32 KB
  __shared__ int   toksL[128];
  __shared__ float sclL[128];

  int tid = threadIdx.x, lane = tid & 63, wid = tid >> 6;

  if (tid < 128) {
    int i = i0 + tid; if (i > cnt - 1) i = cnt - 1;  // pad rows duplicate last valid
    toksL[tid] = tok_row[rowbase + i];
    if (EPI == 2) sclL[tid] = scale_row[rowbase + i];
  }
  __syncthreads();

  // stage setup: 16 instrs/block (A 0..7, B 8..15), 4 per wave; instr j
  // covers rows j*16..j*16+15, lane -> row j*16+(lane>>2), chunk lane&3,
  // source chunk XOR-swizzled by (row>>1)&3.
  const char* gsrc[4];
  int ldsoff[4];
  int rsub = lane >> 2, chunk = lane & 3;
  const char* Bg = (const char*)B + (size_t)g * NDT * KD * 2;
#pragma unroll
  for (int q = 0; q < 4; ++q) {
    int j = wid * 4 + q;
    int row = (j & 7) * 16 + rsub;
    int csw = (chunk ^ ((row >> 1) & 3)) * 16;
    if (j < 8) {
      size_t arow = GATHER ? (size_t)toksL[row] : (size_t)(rowbase + i0 + row);
      gsrc[q] = (const char*)A + arow * (size_t)(KD * 2) + csw;
    } else {
      gsrc[q] = Bg + (size_t)(ct * 128 + row) * (KD * 2) + csw;
    }
    ldsoff[q] = j * 1024;
  }

  f32x4 acc[4][4];
#pragma unroll
  for (int m2 = 0; m2 < 4; ++m2)
#pragma unroll
    for (int n2 = 0; n2 < 4; ++n2) acc[m2][n2] = f32x4{0.f, 0.f, 0.f, 0.f};

  int wr = wid >> 1, wc = wid & 1;   // wave tile 64x64 at (wr*64, wc*64)
  // read byte-offsets within one buffer; chunk = (lane>>4)^((row>>1)&3)
  int rdA[4], rdB[4];
#pragma unroll
  for (int m2 = 0; m2 < 4; ++m2) {
    int row = wr * 64 + m2 * 16 + (lane & 15);
    rdA[m2] = row * 64 + (((lane >> 4) ^ ((row >> 1) & 3)) * 16);
  }
#pragma unroll
  for (int n2 = 0; n2 < 4; ++n2) {
    int row = wc * 64 + n2 * 16 + (lane & 15);
    rdB[n2] = (128 + row) * 64 + (((lane >> 4) ^ ((row >> 1) & 3)) * 16);
  }

  auto stage = [&](int buf, int t) {
#pragma unroll
    for (int q = 0; q < 4; ++q)
      load_lds16(gsrc[q] + (size_t)t * 64, (char*)&Sm[buf][0] + ldsoff[q]);
  };
  auto compute = [&](int buf) {
    const char* Sb = (const char*)&Sm[buf][0];
    bf16x8 af[4], bfr[4];
#pragma unroll
    for (int m2 = 0; m2 < 4; ++m2) af[m2] = *(const bf16x8*)(Sb + rdA[m2]);
#pragma unroll
    for (int n2 = 0; n2 < 4; ++n2) bfr[n2] = *(const bf16x8*)(Sb + rdB[n2]);
#pragma unroll
    for (int m2 = 0; m2 < 4; ++m2)
#pragma unroll
      for (int n2 = 0; n2 < 4; ++n2)
        acc[m2][n2] = __builtin_amdgcn_mfma_f32_16x16x32_bf16(af[m2], bfr[n2], acc[m2][n2], 0, 0, 0);
  };

  // dbuf stage-ahead: one barrier per step; compiler's vmcnt(0)+lgkmcnt(0)
  // at each __syncthreads gives both the RAW (stage t+1 done) and WAR
  // (this step's ds_reads done) guarantees.
  stage(0, 0);
  __syncthreads();
#pragma unroll 2
  for (int t = 0; t < T; ++t) {
    if (t + 1 < T) stage((t + 1) & 1, t + 1);
    __builtin_amdgcn_sched_barrier(0);   // pin stage-issue before compute's ds_reads
    compute(t & 1);
    __syncthreads();
  }

  // epilogue; C/D frag: col = lane&15, row = (lane>>4)*4 + reg  [verified m89/m91]
#pragma unroll
  for (int m2 = 0; m2 < 4; ++m2) {
    int rb = wr * 64 + m2 * 16 + ((lane >> 4) << 2);
#pragma unroll
    for (int n2 = 0; n2 < 4; ++n2) {
      int col = ct * 128 + wc * 64 + n2 * 16 + (lane & 15);
#pragma unroll
      for (int r = 0; r < 4; ++r) {
        int grow = i0 + rb + r;
        if (grow < cnt) {
          float v = acc[m2][n2][r];
          if constexpr (EPI == 1) {
            v = fmaxf(v, 0.f);
            Hout[(size_t)(rowbase + grow) * NDT + col] = (__bf16)(v * v);
          } else {
            atomicAdd(&Yout[(size_t)toksL[rb + r] * NDT + col], v * sclL[rb + r]);
          }
        }
      }
    }
  }
}

extern "C" void kernel_launch(void* const* d_in, const int* in_sizes, int n_in,
                              void* d_out, int out_size, void* d_ws, size_t ws_size,
                              hipStream_t stream) {
  const float* x      = (const float*)d_in[0];
  const float* rw     = (const float*)d_in[1];
  const float* wfc    = (const float*)d_in[2];
  const float* wproj  = (const float*)d_in[3];
  const float* wsfc   = (const float*)d_in[4];
  const float* wsproj = (const float*)d_in[5];
  float* y = (float*)d_out;

  char* ws = (char*)d_ws;
  size_t off = 0;
  auto alloc = [&](size_t bytes) {
    void* p = ws + off;
    off += (bytes + 1023) & ~(size_t)1023;
    return p;
  };
  __bf16* xbf      = (__bf16*)alloc((size_t)NTOK * DDIM * 2);          // 16 MB
  __bf16* B1       = (__bf16*)alloc((size_t)9 * HDIM * DDIM * 2);      // 26 MB [9][1408][1024]
  __bf16* B2       = (__bf16*)alloc((size_t)9 * DDIM * HDIM * 2);      // 26 MB [9][1024][1408]
  __bf16* H        = (__bf16*)alloc((size_t)NROWS * HDIM * 2);         // 81 MB
  int*    tok_row  = (int*)alloc((size_t)NROWS * 4);
  float*  scale_row= (float*)alloc((size_t)NROWS * 4);
  int2*   e01      = (int2*)alloc((size_t)NTOK * 8);
  float2* p01      = (float2*)alloc((size_t)NTOK * 8);
  int*    counts   = (int*)alloc(1024);
  float*  psum_part= (float*)alloc(256 * 8 * 4);
  int*    fcnt_part= (int*)alloc(256 * 8 * 4);
  (void)ws_size; (void)out_size; (void)in_sizes; (void)n_in;

  zero_kernel<<<2048, 256, 0, stream>>>(y);
  // B1: wfc [e][1024][1408] -> [e][1408][1024]; z=8 is wsfc
  tconv2_kernel<<<dim3(44, 16, 9), 256, 0, stream>>>(
      wfc, B1, wsfc, B1 + (size_t)8 * HDIM * DDIM, 1024, 1408);
  // B2: wproj [e][1408][1024] -> [e][1024][1408]; z=8 is wsproj
  tconv2_kernel<<<dim3(32, 22, 9), 256, 0, stream>>>(
      wproj, B2, wsproj, B2 + (size_t)8 * DDIM * HDIM, 1408, 1024);
  router_kernel<<<256, 256, 0, stream>>>(x, rw, xbf, e01, p01, tok_row, scale_row,
                                         psum_part, fcnt_part);
  dispatch_kernel<<<1, 256, 0, stream>>>(e01, p01, tok_row, scale_row, counts,
                                         psum_part, fcnt_part, y + YN);
  // GEMM1: H = relu(gather(x) @ B1)^2 ; 128x128 tiles: (64 + 8*20) rt * 11 ct = 2464
  gemm_kernel<1024, 1408, true, 1><<<2464, 256, 0, stream>>>(
      xbf, B1, H, nullptr, counts, tok_row, scale_row);
  // GEMM2: y[tok] += scale * (H @ B2) ; 128x128 tiles: 224 rt * 8 ct = 1792
  gemm_kernel<1408, 1024, false, 2><<<1792, 256, 0, stream>>>(
      H, B2, nullptr, y, counts, tok_row, scale_row);
}

// Round 16
// 308.331 us; speedup vs baseline: 1.1547x; 1.1547x over previous
//
#include <hip/hip_runtime.h>

// MoE forward, MI355X. fp32 router/dispatch (exact top-k), bf16 MFMA grouped
// GEMMs (9 groups = 8 experts + shared), fp32-atomic scatter-combine.
// R15: GEMMs reverted to the 9x-verified R8/R10/R13 kernel (byte-identical;
// 131us each). R14 lesson: intra-block dbuf regresses vs 4-block cross-block
// overlap (m99/m100 generalize) -- schedule-variation sweep now complete,
// all variants <= plain single-buffer m97 loop. This round trims overhead:
// (1) tconv fused to ONE launch (z=18 selects tensor, geometry guards);
// (2) dispatch stat-reduce parallelized (256-thread shfl butterfly replaces
// 8-thread x 256-iteration serial global loop).

#define NTOK 8192
#define DDIM 1024
#define HDIM 1408
#define CAP  2560
#define NROWS (NTOK + 8*CAP)   // 28672 GEMM rows: [0,8192) shared, then 8*2560 expert slots
#define YN   8388608           // NTOK*DDIM

typedef __bf16 bf16x8 __attribute__((ext_vector_type(8)));
typedef float  f32x4  __attribute__((ext_vector_type(4)));

typedef __attribute__((address_space(1))) void gvoid_t;
typedef __attribute__((address_space(3))) void svoid_t;

static __device__ __forceinline__ void load_lds16(const void* g, void* l) {
  // 16B per lane, LDS dest = wave-uniform base + lane*16 (linear)
  __builtin_amdgcn_global_load_lds((gvoid_t*)g, (svoid_t*)l, 16, 0, 0);
}

// ---------------- zero y ----------------
__global__ __launch_bounds__(256) void zero_kernel(float* __restrict__ y) {
  size_t idx = (size_t)blockIdx.x * 256 + threadIdx.x;
  float4 z = make_float4(0.f, 0.f, 0.f, 0.f);
  float4* p = (float4*)y;
#pragma unroll
  for (int j = 0; j < 4; ++j) p[idx + (size_t)j * 524288] = z;
}

// ------- transpose+convert v3: one launch for all 4 weight tensors -------
// z in [0,18): z<9 -> B1 path (R=1024,C=1408; z<8 expert wfc, z==8 wsfc),
// z>=9 -> B2 path (R=1408,C=1024; z-9<8 expert wproj, z==17 wsproj).
// Grid (44,22,18); B1 blocks need by<16, B2 blocks need bx<32 (guards).
// 64x32 tile, coalesced reads, bf16x8 (16B) vector stores, 2-way-free LDS.
__global__ __launch_bounds__(256) void tconv3_kernel(
    const float* __restrict__ wfc, __bf16* __restrict__ B1,
    const float* __restrict__ wsfc,
    const float* __restrict__ wproj, __bf16* __restrict__ B2,
    const float* __restrict__ wsproj) {
  __shared__ float t[64][33];
  int z = blockIdx.z, tid = threadIdx.x;
  const float* ip;
  __bf16* op;
  int R, C;
  if (z < 9) {
    if (blockIdx.y >= 16) return;          // B1 geometry: 44 x 16
    R = 1024; C = 1408;
    ip = (z < 8) ? wfc + (size_t)z * R * C : wsfc;
    op = (z < 8) ? B1 + (size_t)z * (size_t)C * R : B1 + (size_t)8 * (size_t)C * R;
  } else {
    if (blockIdx.x >= 32) return;          // B2 geometry: 32 x 22
    R = 1408; C = 1024;
    int e = z - 9;
    ip = (e < 8) ? wproj + (size_t)e * R * C : wsproj;
    op = (e < 8) ? B2 + (size_t)e * (size_t)C * R : B2 + (size_t)8 * (size_t)C * R;
  }
  int c0 = blockIdx.x * 32, r0 = blockIdx.y * 64;
  int tx = tid & 31, ty = tid >> 5;          // read: 8 rows/pass, 128B/row coalesced
#pragma unroll
  for (int k = 0; k < 8; ++k)
    t[ty + k * 8][tx] = ip[(size_t)(r0 + ty + k * 8) * C + c0 + tx];
  __syncthreads();
  int cl = tid >> 3, rq = (tid & 7) * 8;     // write: one bf16x8 (16B) per thread
  bf16x8 o;                                  // LDS bank = (8q+j+p)%32 -> 2-way (free)
#pragma unroll
  for (int j = 0; j < 8; ++j) o[j] = (__bf16)t[rq + j][cl];
  *(bf16x8*)(op + (size_t)(c0 + cl) * R + r0 + rq) = o;
}

// ------- router (+ fused x->bf16 convert): fp32 logits, softmax, top-2, renorm -------
__global__ __launch_bounds__(256) void router_kernel(
    const float* __restrict__ x, const float* __restrict__ rw,
    __bf16* __restrict__ xbf,
    int2* __restrict__ e01, float2* __restrict__ p01,
    int* __restrict__ tok_row, float* __restrict__ scale_row,
    float* __restrict__ psum_part, int* __restrict__ fcnt_part) {
  __shared__ float rwl[8 * 1024];
  __shared__ float ps[8];
  __shared__ int fc[8];
  int tid = threadIdx.x;
  if (tid < 8) { ps[tid] = 0.f; fc[tid] = 0; }
  float4* rl4 = (float4*)rwl;
  const float4* rg4 = (const float4*)rw;
#pragma unroll
  for (int j = 0; j < 8; ++j) rl4[tid + 256 * j] = rg4[tid + 256 * j];
  __syncthreads();
  int lane = tid & 63, wid = tid >> 6;
  for (int it = 0; it < 8; ++it) {
    int t = blockIdx.x * 32 + wid * 8 + it;
    const float4* xt = (const float4*)(x + (size_t)t * DDIM);
    float a[8];
#pragma unroll
    for (int e = 0; e < 8; ++e) a[e] = 0.f;
    float4 v[4];
#pragma unroll
    for (int jj = 0; jj < 4; ++jj) {
      v[jj] = xt[lane * 4 + jj];
#pragma unroll
      for (int e = 0; e < 8; ++e) {
        float4 w = rl4[e * 256 + lane * 4 + jj];
        a[e] += v[jj].x * w.x + v[jj].y * w.y + v[jj].z * w.z + v[jj].w * w.w;
      }
    }
    {
      bf16x8 o0, o1;
#pragma unroll
      for (int jj = 0; jj < 2; ++jj) {
        o0[jj * 4 + 0] = (__bf16)v[jj].x; o0[jj * 4 + 1] = (__bf16)v[jj].y;
        o0[jj * 4 + 2] = (__bf16)v[jj].z; o0[jj * 4 + 3] = (__bf16)v[jj].w;
        o1[jj * 4 + 0] = (__bf16)v[jj + 2].x; o1[jj * 4 + 1] = (__bf16)v[jj + 2].y;
        o1[jj * 4 + 2] = (__bf16)v[jj + 2].z; o1[jj * 4 + 3] = (__bf16)v[jj + 2].w;
      }
      __bf16* xo = xbf + (size_t)t * DDIM + lane * 16;
      *(bf16x8*)xo = o0;
      *(bf16x8*)(xo + 8) = o1;
    }
#pragma unroll
    for (int off = 32; off >= 1; off >>= 1)
#pragma unroll
      for (int e = 0; e < 8; ++e) a[e] += __shfl_xor(a[e], off);
    if (lane == 0) {
      int am = 0; float m = a[0];
      for (int e = 1; e < 8; ++e) if (a[e] > m) { m = a[e]; am = e; }
      float s = 0.f, ex[8];
      for (int e = 0; e < 8; ++e) { ex[e] = expf(a[e] - m); s += ex[e]; }
      float inv = 1.f / s;
      int am2 = -1; float m2 = -3.4e38f;
      for (int e = 0; e < 8; ++e) if (e != am && a[e] > m2) { m2 = a[e]; am2 = e; }
      float p0 = ex[am] * inv, p1 = ex[am2] * inv;
      float rn = 1.f / (p0 + p1 + 1e-9f);
      e01[t] = make_int2(am, am2);
      p01[t] = make_float2(p0 * rn, p1 * rn);
      tok_row[t] = t;            // shared-group rows: identity gather, weight 1
      scale_row[t] = 1.f;
      atomicAdd(&fc[am], 1);
      for (int e = 0; e < 8; ++e) atomicAdd(&ps[e], ex[e] * inv);
    }
  }
  __syncthreads();
  if (tid < 8) { psum_part[blockIdx.x * 8 + tid] = ps[tid]; fcnt_part[blockIdx.x * 8 + tid] = fc[tid]; }
}

// ------- dispatch (+stat reduce +aux): stable rank within expert, capacity drop -------
// Stat reduce parallelized: thread t loads block t's 8 partials, butterfly
// shfl_xor across the wave, 4-wave combine in LDS (was: 8 threads x 256
// serial global loads).
__global__ __launch_bounds__(256) void dispatch_kernel(
    const int2* __restrict__ e01, const float2* __restrict__ p01,
    int* __restrict__ tok_row, float* __restrict__ scale_row, int* __restrict__ counts,
    const float* __restrict__ psum_part, const int* __restrict__ fcnt_part,
    float* __restrict__ aux_out) {
  __shared__ int lcnt[256][8];
  __shared__ float wps[4][8];
  __shared__ int wfcs[4][8];
  __shared__ float aps[8];
  __shared__ int afc[8];
  int tid = threadIdx.x, lane = tid & 63, w = tid >> 6;
  // parallel stat reduce
  float s[8]; int c[8];
#pragma unroll
  for (int e = 0; e < 8; ++e) { s[e] = psum_part[tid * 8 + e]; c[e] = fcnt_part[tid * 8 + e]; }
#pragma unroll
  for (int off = 32; off >= 1; off >>= 1)
#pragma unroll
    for (int e = 0; e < 8; ++e) { s[e] += __shfl_xor(s[e], off); c[e] += __shfl_xor(c[e], off); }
  if (lane == 0) {
#pragma unroll
    for (int e = 0; e < 8; ++e) { wps[w][e] = s[e]; wfcs[w][e] = c[e]; }
  }
  // histogram phase
  int my[8];
#pragma unroll
  for (int e = 0; e < 8; ++e) my[e] = 0;
  int base = tid * 64;  // 256 threads * 64 entries = 16384 = N*K, contiguous => stable
  for (int j = 0; j < 64; ++j) {
    int ent = base + j; int t = ent >> 1;
    int2 ee = e01[t];
    int ex = (ent & 1) ? ee.y : ee.x;
    my[ex]++;
  }
#pragma unroll
  for (int e = 0; e < 8; ++e) lcnt[tid][e] = my[e];
  __syncthreads();
  if (tid < 8) {
    aps[tid] = wps[0][tid] + wps[1][tid] + wps[2][tid] + wps[3][tid];
    afc[tid] = wfcs[0][tid] + wfcs[1][tid] + wfcs[2][tid] + wfcs[3][tid];
    int run = 0;
    for (int i = 0; i < 256; ++i) { int cc = lcnt[i][tid]; lcnt[i][tid] = run; run += cc; }
    counts[tid] = run < CAP ? run : CAP;
  }
  __syncthreads();
  int offs[8];
#pragma unroll
  for (int e = 0; e < 8; ++e) offs[e] = lcnt[tid][e];
  for (int j = 0; j < 64; ++j) {
    int ent = base + j; int t = ent >> 1; int k = ent & 1;
    int2 ee = e01[t];
    int ex = k ? ee.y : ee.x;
    float pr = k ? p01[t].y : p01[t].x;
    int pos = offs[ex]++;
    if (pos < CAP) {
      int row = NTOK + ex * CAP + pos;
      tok_row[row] = t;
      scale_row[row] = pr;
    }
  }
  if (tid == 0) {
    float t = 0.f;
    for (int e = 0; e < 8; ++e) t += ((float)afc[e] / 8192.f) * (aps[e] / 8192.f);
    *aux_out = 0.08f * t;  // AUX_COEF * E = 0.01 * 8
  }
}

// ---------------- grouped GEMM, 128x128 tile, BK=64, 4 waves, single-buffer (m97 structure) ----------------
// R8/R10/R13-verified (131us x9 runs). Per K-step: 8 global_load_lds/wave ->
// __syncthreads (compiler emits vmcnt(0)) -> 16 ds_read_b128 + 32 MFMA ->
// __syncthreads. Latency hiding via 4 resident blocks/CU (33KB LDS,
// launch_bounds(256,4): VGPR cap 512/4 = 128 >= ~124 used -- do NOT raise
// waves/EU, acc spills: R9; do NOT dbuf, regresses: R14). XOR chunk-swizzle:
// LDS[row][c] = global[row][c^(row&7)] (16B chunks), staged via swizzled
// per-lane SOURCE, read with matching XOR (0 conflicts).
// EPI==1: H = bf16(relu(acc)^2)   EPI==2: atomicAdd(y[tok][col], acc*scale)
template <int KD, int NDT, bool GATHER, int EPI>
__global__ __launch_bounds__(256, 4) void gemm_kernel(
    const __bf16* __restrict__ A, const __bf16* __restrict__ B,
    __bf16* __restrict__ Hout, float* __restrict__ Yout,
    const int* __restrict__ counts, const int* __restrict__ tok_row,
    const float* __restrict__ scale_row) {
  constexpr int NCT = NDT / 128;
  constexpr int SH = NTOK / 128;   // 64 shared row-tiles
  constexpr int ET = CAP / 128;    // 20 expert row-tiles (worst case)
  // XCD bijective remap + 4-rt chunks (nwg%8==0, nwg%(4*NCT)==0 hold)
  int nwg = gridDim.x;
  int lin = (blockIdx.x & 7) * (nwg >> 3) + (blockIdx.x >> 3);
  int rem = lin % (4 * NCT);
  int rt = (lin / (4 * NCT)) * 4 + (rem & 3);
  int ct = rem >> 2;

  int g, i0, rowbase;
  if (rt < SH) { g = 8; rowbase = 0; i0 = rt << 7; }
  else { int r = rt - SH; g = r / ET; i0 = (r % ET) << 7; rowbase = NTOK + g * CAP; }
  int cnt = (g == 8) ? NTOK : counts[g];
  if (i0 >= cnt) return;  // uniform early-exit

  __shared__ __align__(16) __bf16 As[128 * 64];   // 16 KB
  __shared__ __align__(16) __bf16 Bs[128 * 64];   // 16 KB
  __shared__ int   toksL[128];
  __shared__ float sclL[128];

  int tid = threadIdx.x, lane = tid & 63, wid = tid >> 6;

  if (tid < 128) {
    int i = i0 + tid; if (i > cnt - 1) i = cnt - 1;  // pad rows duplicate last valid
    toksL[tid] = tok_row[rowbase + i];
    if (EPI == 2) sclL[tid] = scale_row[rowbase + i];
  }
  __syncthreads();

  // staging pointers: 8 lanes cover one 128B k-row; 16B chunk swizzled by row&7
  int rsub = lane >> 3, csub = lane & 7;
  int csw = (csub ^ rsub) * 16;
  const char* aP[4];
  const char* bP[4];
  const char* Bg = (const char*)B + (size_t)g * NDT * KD * 2;
#pragma unroll
  for (int t = 0; t < 4; ++t) {
    int ia = wid * 32 + t * 8 + rsub;
    size_t arow = GATHER ? (size_t)toksL[ia] : (size_t)(rowbase + i0 + ia);
    aP[t] = (const char*)A + arow * (size_t)(KD * 2) + csw;
    int ib = ct * 128 + wid * 32 + t * 8 + rsub;
    bP[t] = Bg + (size_t)ib * (KD * 2) + csw;
  }

  f32x4 acc[4][4];
#pragma unroll
  for (int m2 = 0; m2 < 4; ++m2)
#pragma unroll
    for (int n2 = 0; n2 < 4; ++n2) acc[m2][n2] = f32x4{0.f, 0.f, 0.f, 0.f};

  int wr = wid >> 1, wc = wid & 1;   // wave tile 64x64 at (wr*64, wc*64)
  // hoisted LDS read offsets (element units); chunk' = chunk ^ (row&7), row&7 == lane&7
  int rA[4], rB[4], cS[2];
#pragma unroll
  for (int m2 = 0; m2 < 4; ++m2) rA[m2] = (wr * 64 + m2 * 16 + (lane & 15)) * 64;
#pragma unroll
  for (int n2 = 0; n2 < 4; ++n2) rB[n2] = (wc * 64 + n2 * 16 + (lane & 15)) * 64;
#pragma unroll
  for (int kk = 0; kk < 2; ++kk) cS[kk] = ((kk * 4 + (lane >> 4)) ^ (lane & 7)) * 8;

  // m97 structure: stage -> sync -> compute -> sync, single buffer.
  for (int k0 = 0; k0 < KD; k0 += 64) {
    size_t kb = (size_t)k0 * 2;
#pragma unroll
    for (int t = 0; t < 4; ++t) {
      load_lds16(aP[t] + kb, &As[(wid * 32 + t * 8) * 64]);
      load_lds16(bP[t] + kb, &Bs[(wid * 32 + t * 8) * 64]);
    }
    __syncthreads();   // compiler inserts s_waitcnt vmcnt(0) before barrier
#pragma unroll
    for (int kk = 0; kk < 2; ++kk) {
      bf16x8 af[4], bfr[4];
#pragma unroll
      for (int m2 = 0; m2 < 4; ++m2) af[m2] = *(const bf16x8*)&As[rA[m2] + cS[kk]];
#pragma unroll
      for (int n2 = 0; n2 < 4; ++n2) bfr[n2] = *(const bf16x8*)&Bs[rB[n2] + cS[kk]];
#pragma unroll
      for (int m2 = 0; m2 < 4; ++m2)
#pragma unroll
        for (int n2 = 0; n2 < 4; ++n2)
          acc[m2][n2] = __builtin_amdgcn_mfma_f32_16x16x32_bf16(af[m2], bfr[n2], acc[m2][n2], 0, 0, 0);
    }
    __syncthreads();   // protect LDS reuse next iteration
  }

  // epilogue; C/D frag: col = lane&15, row = (lane>>4)*4 + reg  [verified m89/m91]
#pragma unroll
  for (int m2 = 0; m2 < 4; ++m2) {
    int rb = wr * 64 + m2 * 16 + ((lane >> 4) << 2);
#pragma unroll
    for (int n2 = 0; n2 < 4; ++n2) {
      int col = ct * 128 + wc * 64 + n2 * 16 + (lane & 15);
#pragma unroll
      for (int r = 0; r < 4; ++r) {
        int grow = i0 + rb + r;
        if (grow < cnt) {
          float v = acc[m2][n2][r];
          if constexpr (EPI == 1) {
            v = fmaxf(v, 0.f);
            Hout[(size_t)(rowbase + grow) * NDT + col] = (__bf16)(v * v);
          } else {
            atomicAdd(&Yout[(size_t)toksL[rb + r] * NDT + col], v * sclL[rb + r]);
          }
        }
      }
    }
  }
}

extern "C" void kernel_launch(void* const* d_in, const int* in_sizes, int n_in,
                              void* d_out, int out_size, void* d_ws, size_t ws_size,
                              hipStream_t stream) {
  const float* x      = (const float*)d_in[0];
  const float* rw     = (const float*)d_in[1];
  const float* wfc    = (const float*)d_in[2];
  const float* wproj  = (const float*)d_in[3];
  const float* wsfc   = (const float*)d_in[4];
  const float* wsproj = (const float*)d_in[5];
  float* y = (float*)d_out;

  char* ws = (char*)d_ws;
  size_t off = 0;
  auto alloc = [&](size_t bytes) {
    void* p = ws + off;
    off += (bytes + 1023) & ~(size_t)1023;
    return p;
  };
  __bf16* xbf      = (__bf16*)alloc((size_t)NTOK * DDIM * 2);          // 16 MB
  __bf16* B1       = (__bf16*)alloc((size_t)9 * HDIM * DDIM * 2);      // 26 MB [9][1408][1024]
  __bf16* B2       = (__bf16*)alloc((size_t)9 * DDIM * HDIM * 2);      // 26 MB [9][1024][1408]
  __bf16* H        = (__bf16*)alloc((size_t)NROWS * HDIM * 2);         // 81 MB
  int*    tok_row  = (int*)alloc((size_t)NROWS * 4);
  float*  scale_row= (float*)alloc((size_t)NROWS * 4);
  int2*   e01      = (int2*)alloc((size_t)NTOK * 8);
  float2* p01      = (float2*)alloc((size_t)NTOK * 8);
  int*    counts   = (int*)alloc(1024);
  float*  psum_part= (float*)alloc(256 * 8 * 4);
  int*    fcnt_part= (int*)alloc(256 * 8 * 4);
  (void)ws_size; (void)out_size; (void)in_sizes; (void)n_in;

  zero_kernel<<<2048, 256, 0, stream>>>(y);
  // all 4 weight transposes in one launch: z<9 -> B1 (44x16 used), z>=9 -> B2 (32x22 used)
  tconv3_kernel<<<dim3(44, 22, 18), 256, 0, stream>>>(wfc, B1, wsfc, wproj, B2, wsproj);
  router_kernel<<<256, 256, 0, stream>>>(x, rw, xbf, e01, p01, tok_row, scale_row,
                                         psum_part, fcnt_part);
  dispatch_kernel<<<1, 256, 0, stream>>>(e01, p01, tok_row, scale_row, counts,
                                         psum_part, fcnt_part, y + YN);
  // GEMM1: H = relu(gather(x) @ B1)^2 ; 128x128 tiles: (64 + 8*20) rt * 11 ct = 2464
  gemm_kernel<1024, 1408, true, 1><<<2464, 256, 0, stream>>>(
      xbf, B1, H, nullptr, counts, tok_row, scale_row);
  // GEMM2: y[tok] += scale * (H @ B2) ; 128x128 tiles: 224 rt * 8 ct = 1792
  gemm_kernel<1408, 1024, false, 2><<<1792, 256, 0, stream>>>(
      H, B2, nullptr, y, counts, tok_row, scale_row);
}

// Round 17
// 305.808 us; speedup vs baseline: 1.1642x; 1.0082x over previous
//
#include <hip/hip_runtime.h>

// MoE forward, MI355X. fp32 router/dispatch (exact top-k), bf16 MFMA grouped
// GEMMs (9 groups = 8 experts + shared), fp32-atomic scatter-combine.
// R16: zero-elimination. GEMM2 split: (a) shared group (identity rows, each
// y element exactly once) PLAIN-stores y -- replaces the 32MB zero_kernel;
// (b) expert group atomicAdds on top (same-stream order guarantees store
// before add). GEMM structure byte-identical to R8/R10/R13/R15 (131us x11
// runs): 128x128, BK=64, 4 waves, single-buffer, 4 blocks/CU. Lessons kept:
// no >4 waves/EU (R9 spills), no dbuf (R14), no mega-fusion (R11/R12).

#define NTOK 8192
#define DDIM 1024
#define HDIM 1408
#define CAP  2560
#define NROWS (NTOK + 8*CAP)   // 28672 GEMM rows: [0,8192) shared, then 8*2560 expert slots
#define YN   8388608           // NTOK*DDIM

typedef __bf16 bf16x8 __attribute__((ext_vector_type(8)));
typedef float  f32x4  __attribute__((ext_vector_type(4)));

typedef __attribute__((address_space(1))) void gvoid_t;
typedef __attribute__((address_space(3))) void svoid_t;

static __device__ __forceinline__ void load_lds16(const void* g, void* l) {
  // 16B per lane, LDS dest = wave-uniform base + lane*16 (linear)
  __builtin_amdgcn_global_load_lds((gvoid_t*)g, (svoid_t*)l, 16, 0, 0);
}

// ------- transpose+convert v3: one launch for all 4 weight tensors -------
// z in [0,18): z<9 -> B1 path (R=1024,C=1408; z<8 expert wfc, z==8 wsfc),
// z>=9 -> B2 path (R=1408,C=1024; z-9<8 expert wproj, z==17 wsproj).
// Grid (44,22,18); B1 blocks need by<16, B2 blocks need bx<32 (guards).
// 64x32 tile, coalesced reads, bf16x8 (16B) vector stores, 2-way-free LDS.
__global__ __launch_bounds__(256) void tconv3_kernel(
    const float* __restrict__ wfc, __bf16* __restrict__ B1,
    const float* __restrict__ wsfc,
    const float* __restrict__ wproj, __bf16* __restrict__ B2,
    const float* __restrict__ wsproj) {
  __shared__ float t[64][33];
  int z = blockIdx.z, tid = threadIdx.x;
  const float* ip;
  __bf16* op;
  int R, C;
  if (z < 9) {
    if (blockIdx.y >= 16) return;          // B1 geometry: 44 x 16
    R = 1024; C = 1408;
    ip = (z < 8) ? wfc + (size_t)z * R * C : wsfc;
    op = (z < 8) ? B1 + (size_t)z * (size_t)C * R : B1 + (size_t)8 * (size_t)C * R;
  } else {
    if (blockIdx.x >= 32) return;          // B2 geometry: 32 x 22
    R = 1408; C = 1024;
    int e = z - 9;
    ip = (e < 8) ? wproj + (size_t)e * R * C : wsproj;
    op = (e < 8) ? B2 + (size_t)e * (size_t)C * R : B2 + (size_t)8 * (size_t)C * R;
  }
  int c0 = blockIdx.x * 32, r0 = blockIdx.y * 64;
  int tx = tid & 31, ty = tid >> 5;          // read: 8 rows/pass, 128B/row coalesced
#pragma unroll
  for (int k = 0; k < 8; ++k)
    t[ty + k * 8][tx] = ip[(size_t)(r0 + ty + k * 8) * C + c0 + tx];
  __syncthreads();
  int cl = tid >> 3, rq = (tid & 7) * 8;     // write: one bf16x8 (16B) per thread
  bf16x8 o;                                  // LDS bank = (8q+j+p)%32 -> 2-way (free)
#pragma unroll
  for (int j = 0; j < 8; ++j) o[j] = (__bf16)t[rq + j][cl];
  *(bf16x8*)(op + (size_t)(c0 + cl) * R + r0 + rq) = o;
}

// ------- router (+ fused x->bf16 convert): fp32 logits, softmax, top-2, renorm -------
__global__ __launch_bounds__(256) void router_kernel(
    const float* __restrict__ x, const float* __restrict__ rw,
    __bf16* __restrict__ xbf,
    int2* __restrict__ e01, float2* __restrict__ p01,
    int* __restrict__ tok_row, float* __restrict__ scale_row,
    float* __restrict__ psum_part, int* __restrict__ fcnt_part) {
  __shared__ float rwl[8 * 1024];
  __shared__ float ps[8];
  __shared__ int fc[8];
  int tid = threadIdx.x;
  if (tid < 8) { ps[tid] = 0.f; fc[tid] = 0; }
  float4* rl4 = (float4*)rwl;
  const float4* rg4 = (const float4*)rw;
#pragma unroll
  for (int j = 0; j < 8; ++j) rl4[tid + 256 * j] = rg4[tid + 256 * j];
  __syncthreads();
  int lane = tid & 63, wid = tid >> 6;
  for (int it = 0; it < 8; ++it) {
    int t = blockIdx.x * 32 + wid * 8 + it;
    const float4* xt = (const float4*)(x + (size_t)t * DDIM);
    float a[8];
#pragma unroll
    for (int e = 0; e < 8; ++e) a[e] = 0.f;
    float4 v[4];
#pragma unroll
    for (int jj = 0; jj < 4; ++jj) {
      v[jj] = xt[lane * 4 + jj];
#pragma unroll
      for (int e = 0; e < 8; ++e) {
        float4 w = rl4[e * 256 + lane * 4 + jj];
        a[e] += v[jj].x * w.x + v[jj].y * w.y + v[jj].z * w.z + v[jj].w * w.w;
      }
    }
    {
      bf16x8 o0, o1;
#pragma unroll
      for (int jj = 0; jj < 2; ++jj) {
        o0[jj * 4 + 0] = (__bf16)v[jj].x; o0[jj * 4 + 1] = (__bf16)v[jj].y;
        o0[jj * 4 + 2] = (__bf16)v[jj].z; o0[jj * 4 + 3] = (__bf16)v[jj].w;
        o1[jj * 4 + 0] = (__bf16)v[jj + 2].x; o1[jj * 4 + 1] = (__bf16)v[jj + 2].y;
        o1[jj * 4 + 2] = (__bf16)v[jj + 2].z; o1[jj * 4 + 3] = (__bf16)v[jj + 2].w;
      }
      __bf16* xo = xbf + (size_t)t * DDIM + lane * 16;
      *(bf16x8*)xo = o0;
      *(bf16x8*)(xo + 8) = o1;
    }
#pragma unroll
    for (int off = 32; off >= 1; off >>= 1)
#pragma unroll
      for (int e = 0; e < 8; ++e) a[e] += __shfl_xor(a[e], off);
    if (lane == 0) {
      int am = 0; float m = a[0];
      for (int e = 1; e < 8; ++e) if (a[e] > m) { m = a[e]; am = e; }
      float s = 0.f, ex[8];
      for (int e = 0; e < 8; ++e) { ex[e] = expf(a[e] - m); s += ex[e]; }
      float inv = 1.f / s;
      int am2 = -1; float m2 = -3.4e38f;
      for (int e = 0; e < 8; ++e) if (e != am && a[e] > m2) { m2 = a[e]; am2 = e; }
      float p0 = ex[am] * inv, p1 = ex[am2] * inv;
      float rn = 1.f / (p0 + p1 + 1e-9f);
      e01[t] = make_int2(am, am2);
      p01[t] = make_float2(p0 * rn, p1 * rn);
      tok_row[t] = t;            // shared-group rows: identity gather, weight 1
      scale_row[t] = 1.f;
      atomicAdd(&fc[am], 1);
      for (int e = 0; e < 8; ++e) atomicAdd(&ps[e], ex[e] * inv);
    }
  }
  __syncthreads();
  if (tid < 8) { psum_part[blockIdx.x * 8 + tid] = ps[tid]; fcnt_part[blockIdx.x * 8 + tid] = fc[tid]; }
}

// ------- dispatch (+stat reduce +aux): stable rank within expert, capacity drop -------
__global__ __launch_bounds__(256) void dispatch_kernel(
    const int2* __restrict__ e01, const float2* __restrict__ p01,
    int* __restrict__ tok_row, float* __restrict__ scale_row, int* __restrict__ counts,
    const float* __restrict__ psum_part, const int* __restrict__ fcnt_part,
    float* __restrict__ aux_out) {
  __shared__ int lcnt[256][8];
  __shared__ float wps[4][8];
  __shared__ int wfcs[4][8];
  __shared__ float aps[8];
  __shared__ int afc[8];
  int tid = threadIdx.x, lane = tid & 63, w = tid >> 6;
  // parallel stat reduce
  float s[8]; int c[8];
#pragma unroll
  for (int e = 0; e < 8; ++e) { s[e] = psum_part[tid * 8 + e]; c[e] = fcnt_part[tid * 8 + e]; }
#pragma unroll
  for (int off = 32; off >= 1; off >>= 1)
#pragma unroll
    for (int e = 0; e < 8; ++e) { s[e] += __shfl_xor(s[e], off); c[e] += __shfl_xor(c[e], off); }
  if (lane == 0) {
#pragma unroll
    for (int e = 0; e < 8; ++e) { wps[w][e] = s[e]; wfcs[w][e] = c[e]; }
  }
  // histogram phase
  int my[8];
#pragma unroll
  for (int e = 0; e < 8; ++e) my[e] = 0;
  int base = tid * 64;  // 256 threads * 64 entries = 16384 = N*K, contiguous => stable
  for (int j = 0; j < 64; ++j) {
    int ent = base + j; int t = ent >> 1;
    int2 ee = e01[t];
    int ex = (ent & 1) ? ee.y : ee.x;
    my[ex]++;
  }
#pragma unroll
  for (int e = 0; e < 8; ++e) lcnt[tid][e] = my[e];
  __syncthreads();
  if (tid < 8) {
    aps[tid] = wps[0][tid] + wps[1][tid] + wps[2][tid] + wps[3][tid];
    afc[tid] = wfcs[0][tid] + wfcs[1][tid] + wfcs[2][tid] + wfcs[3][tid];
    int run = 0;
    for (int i = 0; i < 256; ++i) { int cc = lcnt[i][tid]; lcnt[i][tid] = run; run += cc; }
    counts[tid] = run < CAP ? run : CAP;
  }
  __syncthreads();
  int offs[8];
#pragma unroll
  for (int e = 0; e < 8; ++e) offs[e] = lcnt[tid][e];
  for (int j = 0; j < 64; ++j) {
    int ent = base + j; int t = ent >> 1; int k = ent & 1;
    int2 ee = e01[t];
    int ex = k ? ee.y : ee.x;
    float pr = k ? p01[t].y : p01[t].x;
    int pos = offs[ex]++;
    if (pos < CAP) {
      int row = NTOK + ex * CAP + pos;
      tok_row[row] = t;
      scale_row[row] = pr;
    }
  }
  if (tid == 0) {
    float t = 0.f;
    for (int e = 0; e < 8; ++e) t += ((float)afc[e] / 8192.f) * (aps[e] / 8192.f);
    *aux_out = 0.08f * t;  // AUX_COEF * E = 0.01 * 8
  }
}

// ---------------- grouped GEMM, 128x128 tile, BK=64, 4 waves, single-buffer (m97 structure) ----------------
// R8/R10/R13/R15-verified. Per K-step: 8 global_load_lds/wave -> __syncthreads
// (compiler emits vmcnt(0)) -> 16 ds_read_b128 + 32 MFMA -> __syncthreads.
// Latency hiding via 4 resident blocks/CU (33KB LDS, launch_bounds(256,4):
// VGPR cap 512/4 = 128 >= ~124 used -- do NOT raise waves/EU: R9 spills;
// do NOT dbuf: R14 regresses). XOR chunk-swizzle: LDS[row][c] =
// global[row][c^(row&7)] (16B chunks), staged via swizzled per-lane SOURCE,
// read with matching XOR (0 conflicts).
// RANGE: 0 = shared+expert tiles (GEMM1), 1 = shared-only, 2 = expert-only.
// EPI: 1 = H-store bf16(relu^2); 2 = atomicAdd(y, v*scale); 3 = plain store y.
template <int KD, int NDT, bool GATHER, int EPI, int RANGE>
__global__ __launch_bounds__(256, 4) void gemm_kernel(
    const __bf16* __restrict__ A, const __bf16* __restrict__ B,
    __bf16* __restrict__ Hout, float* __restrict__ Yout,
    const int* __restrict__ counts, const int* __restrict__ tok_row,
    const float* __restrict__ scale_row) {
  constexpr int NCT = NDT / 128;
  constexpr int SH = NTOK / 128;   // 64 shared row-tiles
  constexpr int ET = CAP / 128;    // 20 expert row-tiles (worst case)
  // XCD bijective remap + 4-rt chunks (nwg%8==0, nwg%(4*NCT)==0 hold)
  int nwg = gridDim.x;
  int lin = (blockIdx.x & 7) * (nwg >> 3) + (blockIdx.x >> 3);
  int rem = lin % (4 * NCT);
  int rt = (lin / (4 * NCT)) * 4 + (rem & 3);
  int ct = rem >> 2;

  int g, i0, rowbase;
  if (RANGE == 1) { g = 8; rowbase = 0; i0 = rt << 7; }
  else if (RANGE == 2) { g = rt / ET; i0 = (rt % ET) << 7; rowbase = NTOK + g * CAP; }
  else {
    if (rt < SH) { g = 8; rowbase = 0; i0 = rt << 7; }
    else { int r = rt - SH; g = r / ET; i0 = (r % ET) << 7; rowbase = NTOK + g * CAP; }
  }
  int cnt = (g == 8) ? NTOK : counts[g];
  if (i0 >= cnt) return;  // uniform early-exit

  __shared__ __align__(16) __bf16 As[128 * 64];   // 16 KB
  __shared__ __align__(16) __bf16 Bs[128 * 64];   // 16 KB
  __shared__ int   toksL[128];
  __shared__ float sclL[128];

  int tid = threadIdx.x, lane = tid & 63, wid = tid >> 6;

  if (RANGE != 1 && tid < 128) {
    int i = i0 + tid; if (i > cnt - 1) i = cnt - 1;  // pad rows duplicate last valid
    toksL[tid] = tok_row[rowbase + i];
    if (EPI == 2) sclL[tid] = scale_row[rowbase + i];
  }
  __syncthreads();

  // staging pointers: 8 lanes cover one 128B k-row; 16B chunk swizzled by row&7
  int rsub = lane >> 3, csub = lane & 7;
  int csw = (csub ^ rsub) * 16;
  const char* aP[4];
  const char* bP[4];
  const char* Bg = (const char*)B + (size_t)g * NDT * KD * 2;
#pragma unroll
  for (int t = 0; t < 4; ++t) {
    int ia = wid * 32 + t * 8 + rsub;
    size_t arow = GATHER ? (size_t)toksL[ia] : (size_t)(rowbase + i0 + ia);
    aP[t] = (const char*)A + arow * (size_t)(KD * 2) + csw;
    int ib = ct * 128 + wid * 32 + t * 8 + rsub;
    bP[t] = Bg + (size_t)ib * (KD * 2) + csw;
  }

  f32x4 acc[4][4];
#pragma unroll
  for (int m2 = 0; m2 < 4; ++m2)
#pragma unroll
    for (int n2 = 0; n2 < 4; ++n2) acc[m2][n2] = f32x4{0.f, 0.f, 0.f, 0.f};

  int wr = wid >> 1, wc = wid & 1;   // wave tile 64x64 at (wr*64, wc*64)
  // hoisted LDS read offsets (element units); chunk' = chunk ^ (row&7), row&7 == lane&7
  int rA[4], rB[4], cS[2];
#pragma unroll
  for (int m2 = 0; m2 < 4; ++m2) rA[m2] = (wr * 64 + m2 * 16 + (lane & 15)) * 64;
#pragma unroll
  for (int n2 = 0; n2 < 4; ++n2) rB[n2] = (wc * 64 + n2 * 16 + (lane & 15)) * 64;
#pragma unroll
  for (int kk = 0; kk < 2; ++kk) cS[kk] = ((kk * 4 + (lane >> 4)) ^ (lane & 7)) * 8;

  // m97 structure: stage -> sync -> compute -> sync, single buffer.
  for (int k0 = 0; k0 < KD; k0 += 64) {
    size_t kb = (size_t)k0 * 2;
#pragma unroll
    for (int t = 0; t < 4; ++t) {
      load_lds16(aP[t] + kb, &As[(wid * 32 + t * 8) * 64]);
      load_lds16(bP[t] + kb, &Bs[(wid * 32 + t * 8) * 64]);
    }
    __syncthreads();   // compiler inserts s_waitcnt vmcnt(0) before barrier
#pragma unroll
    for (int kk = 0; kk < 2; ++kk) {
      bf16x8 af[4], bfr[4];
#pragma unroll
      for (int m2 = 0; m2 < 4; ++m2) af[m2] = *(const bf16x8*)&As[rA[m2] + cS[kk]];
#pragma unroll
      for (int n2 = 0; n2 < 4; ++n2) bfr[n2] = *(const bf16x8*)&Bs[rB[n2] + cS[kk]];
#pragma unroll
      for (int m2 = 0; m2 < 4; ++m2)
#pragma unroll
        for (int n2 = 0; n2 < 4; ++n2)
          acc[m2][n2] = __builtin_amdgcn_mfma_f32_16x16x32_bf16(af[m2], bfr[n2], acc[m2][n2], 0, 0, 0);
    }
    __syncthreads();   // protect LDS reuse next iteration
  }

  // epilogue; C/D frag: col = lane&15, row = (lane>>4)*4 + reg  [verified m89/m91]
#pragma unroll
  for (int m2 = 0; m2 < 4; ++m2) {
    int rb = wr * 64 + m2 * 16 + ((lane >> 4) << 2);
#pragma unroll
    for (int n2 = 0; n2 < 4; ++n2) {
      int col = ct * 128 + wc * 64 + n2 * 16 + (lane & 15);
#pragma unroll
      for (int r = 0; r < 4; ++r) {
        int grow = i0 + rb + r;
        if (grow < cnt) {
          float v = acc[m2][n2][r];
          if constexpr (EPI == 1) {
            v = fmaxf(v, 0.f);
            Hout[(size_t)(rowbase + grow) * NDT + col] = (__bf16)(v * v);
          } else if constexpr (EPI == 3) {
            Yout[(size_t)grow * NDT + col] = v;          // shared: identity rows, weight 1
          } else {
            atomicAdd(&Yout[(size_t)toksL[rb + r] * NDT + col], v * sclL[rb + r]);
          }
        }
      }
    }
  }
}

extern "C" void kernel_launch(void* const* d_in, const int* in_sizes, int n_in,
                              void* d_out, int out_size, void* d_ws, size_t ws_size,
                              hipStream_t stream) {
  const float* x      = (const float*)d_in[0];
  const float* rw     = (const float*)d_in[1];
  const float* wfc    = (const float*)d_in[2];
  const float* wproj  = (const float*)d_in[3];
  const float* wsfc   = (const float*)d_in[4];
  const float* wsproj = (const float*)d_in[5];
  float* y = (float*)d_out;

  char* ws = (char*)d_ws;
  size_t off = 0;
  auto alloc = [&](size_t bytes) {
    void* p = ws + off;
    off += (bytes + 1023) & ~(size_t)1023;
    return p;
  };
  __bf16* xbf      = (__bf16*)alloc((size_t)NTOK * DDIM * 2);          // 16 MB
  __bf16* B1       = (__bf16*)alloc((size_t)9 * HDIM * DDIM * 2);      // 26 MB [9][1408][1024]
  __bf16* B2       = (__bf16*)alloc((size_t)9 * DDIM * HDIM * 2);      // 26 MB [9][1024][1408]
  __bf16* H        = (__bf16*)alloc((size_t)NROWS * HDIM * 2);         // 81 MB
  int*    tok_row  = (int*)alloc((size_t)NROWS * 4);
  float*  scale_row= (float*)alloc((size_t)NROWS * 4);
  int2*   e01      = (int2*)alloc((size_t)NTOK * 8);
  float2* p01      = (float2*)alloc((size_t)NTOK * 8);
  int*    counts   = (int*)alloc(1024);
  float*  psum_part= (float*)alloc(256 * 8 * 4);
  int*    fcnt_part= (int*)alloc(256 * 8 * 4);
  (void)ws_size; (void)out_size; (void)in_sizes; (void)n_in;

  // all 4 weight transposes in one launch: z<9 -> B1 (44x16 used), z>=9 -> B2 (32x22 used)
  tconv3_kernel<<<dim3(44, 22, 18), 256, 0, stream>>>(wfc, B1, wsfc, wproj, B2, wsproj);
  router_kernel<<<256, 256, 0, stream>>>(x, rw, xbf, e01, p01, tok_row, scale_row,
                                         psum_part, fcnt_part);
  dispatch_kernel<<<1, 256, 0, stream>>>(e01, p01, tok_row, scale_row, counts,
                                         psum_part, fcnt_part, y + YN);
  // GEMM1: H = relu(gather(x) @ B1)^2 ; 128x128 tiles: (64 + 8*20) rt * 11 ct = 2464
  gemm_kernel<1024, 1408, true, 1, 0><<<2464, 256, 0, stream>>>(
      xbf, B1, H, nullptr, counts, tok_row, scale_row);
  // GEMM2a (shared): y[tok][col] = H_shared @ B2  (plain store, replaces zero)
  gemm_kernel<1408, 1024, false, 3, 1><<<512, 256, 0, stream>>>(
      H, B2, nullptr, y, counts, tok_row, scale_row);
  // GEMM2b (experts): y[tok][col] += scale * (H_exp @ B2)  (atomicAdd on top)
  gemm_kernel<1408, 1024, false, 2, 2><<<1280, 256, 0, stream>>>(
      H, B2, nullptr, y, counts, tok_row, scale_row);
}

// Round 18
// 305.074 us; speedup vs baseline: 1.1670x; 1.0024x over previous
//
#include <hip/hip_runtime.h>

// MoE forward, MI355X. fp32 router/dispatch (exact top-k), bf16 MFMA grouped
// GEMMs (9 groups = 8 experts + shared), fp32-atomic scatter-combine.
// R17: fix GEMM2a residency. R16 counters: GEMM2a (shared->y plain store)
// had 512 blocks = 2 blocks/CU -> ~57% speed (R2/R8 residency data), ~65-70us
// for 23.6 GF. New gemm2s kernel: 64x128 tiles -> 1024 blocks = 4 blocks/CU,
// wave-tile 64x32 (acc[4][2], ~92 VGPR < 128 cap), same BK=64 single-buffer
// m97 loop + verified swizzle + XCD remap. GEMM1/GEMM2b byte-identical to
// R16 (112us / ~90us). Lessons kept: no >4 waves/EU (R9), no dbuf (R14),
// no mega-fusion (R11/R12), zero-elim via shared-store (R16).

#define NTOK 8192
#define DDIM 1024
#define HDIM 1408
#define CAP  2560
#define NROWS (NTOK + 8*CAP)   // 28672 GEMM rows: [0,8192) shared, then 8*2560 expert slots
#define YN   8388608           // NTOK*DDIM

typedef __bf16 bf16x8 __attribute__((ext_vector_type(8)));
typedef float  f32x4  __attribute__((ext_vector_type(4)));

typedef __attribute__((address_space(1))) void gvoid_t;
typedef __attribute__((address_space(3))) void svoid_t;

static __device__ __forceinline__ void load_lds16(const void* g, void* l) {
  // 16B per lane, LDS dest = wave-uniform base + lane*16 (linear)
  __builtin_amdgcn_global_load_lds((gvoid_t*)g, (svoid_t*)l, 16, 0, 0);
}

// ------- transpose+convert v3: one launch for all 4 weight tensors -------
// z in [0,18): z<9 -> B1 path (R=1024,C=1408; z<8 expert wfc, z==8 wsfc),
// z>=9 -> B2 path (R=1408,C=1024; z-9<8 expert wproj, z==17 wsproj).
// Grid (44,22,18); B1 blocks need by<16, B2 blocks need bx<32 (guards).
__global__ __launch_bounds__(256) void tconv3_kernel(
    const float* __restrict__ wfc, __bf16* __restrict__ B1,
    const float* __restrict__ wsfc,
    const float* __restrict__ wproj, __bf16* __restrict__ B2,
    const float* __restrict__ wsproj) {
  __shared__ float t[64][33];
  int z = blockIdx.z, tid = threadIdx.x;
  const float* ip;
  __bf16* op;
  int R, C;
  if (z < 9) {
    if (blockIdx.y >= 16) return;          // B1 geometry: 44 x 16
    R = 1024; C = 1408;
    ip = (z < 8) ? wfc + (size_t)z * R * C : wsfc;
    op = (z < 8) ? B1 + (size_t)z * (size_t)C * R : B1 + (size_t)8 * (size_t)C * R;
  } else {
    if (blockIdx.x >= 32) return;          // B2 geometry: 32 x 22
    R = 1408; C = 1024;
    int e = z - 9;
    ip = (e < 8) ? wproj + (size_t)e * R * C : wsproj;
    op = (e < 8) ? B2 + (size_t)e * (size_t)C * R : B2 + (size_t)8 * (size_t)C * R;
  }
  int c0 = blockIdx.x * 32, r0 = blockIdx.y * 64;
  int tx = tid & 31, ty = tid >> 5;          // read: 8 rows/pass, 128B/row coalesced
#pragma unroll
  for (int k = 0; k < 8; ++k)
    t[ty + k * 8][tx] = ip[(size_t)(r0 + ty + k * 8) * C + c0 + tx];
  __syncthreads();
  int cl = tid >> 3, rq = (tid & 7) * 8;     // write: one bf16x8 (16B) per thread
  bf16x8 o;                                  // LDS bank = (8q+j+p)%32 -> 2-way (free)
#pragma unroll
  for (int j = 0; j < 8; ++j) o[j] = (__bf16)t[rq + j][cl];
  *(bf16x8*)(op + (size_t)(c0 + cl) * R + r0 + rq) = o;
}

// ------- router (+ fused x->bf16 convert): fp32 logits, softmax, top-2, renorm -------
__global__ __launch_bounds__(256) void router_kernel(
    const float* __restrict__ x, const float* __restrict__ rw,
    __bf16* __restrict__ xbf,
    int2* __restrict__ e01, float2* __restrict__ p01,
    int* __restrict__ tok_row, float* __restrict__ scale_row,
    float* __restrict__ psum_part, int* __restrict__ fcnt_part) {
  __shared__ float rwl[8 * 1024];
  __shared__ float ps[8];
  __shared__ int fc[8];
  int tid = threadIdx.x;
  if (tid < 8) { ps[tid] = 0.f; fc[tid] = 0; }
  float4* rl4 = (float4*)rwl;
  const float4* rg4 = (const float4*)rw;
#pragma unroll
  for (int j = 0; j < 8; ++j) rl4[tid + 256 * j] = rg4[tid + 256 * j];
  __syncthreads();
  int lane = tid & 63, wid = tid >> 6;
  for (int it = 0; it < 8; ++it) {
    int t = blockIdx.x * 32 + wid * 8 + it;
    const float4* xt = (const float4*)(x + (size_t)t * DDIM);
    float a[8];
#pragma unroll
    for (int e = 0; e < 8; ++e) a[e] = 0.f;
    float4 v[4];
#pragma unroll
    for (int jj = 0; jj < 4; ++jj) {
      v[jj] = xt[lane * 4 + jj];
#pragma unroll
      for (int e = 0; e < 8; ++e) {
        float4 w = rl4[e * 256 + lane * 4 + jj];
        a[e] += v[jj].x * w.x + v[jj].y * w.y + v[jj].z * w.z + v[jj].w * w.w;
      }
    }
    {
      bf16x8 o0, o1;
#pragma unroll
      for (int jj = 0; jj < 2; ++jj) {
        o0[jj * 4 + 0] = (__bf16)v[jj].x; o0[jj * 4 + 1] = (__bf16)v[jj].y;
        o0[jj * 4 + 2] = (__bf16)v[jj].z; o0[jj * 4 + 3] = (__bf16)v[jj].w;
        o1[jj * 4 + 0] = (__bf16)v[jj + 2].x; o1[jj * 4 + 1] = (__bf16)v[jj + 2].y;
        o1[jj * 4 + 2] = (__bf16)v[jj + 2].z; o1[jj * 4 + 3] = (__bf16)v[jj + 2].w;
      }
      __bf16* xo = xbf + (size_t)t * DDIM + lane * 16;
      *(bf16x8*)xo = o0;
      *(bf16x8*)(xo + 8) = o1;
    }
#pragma unroll
    for (int off = 32; off >= 1; off >>= 1)
#pragma unroll
      for (int e = 0; e < 8; ++e) a[e] += __shfl_xor(a[e], off);
    if (lane == 0) {
      int am = 0; float m = a[0];
      for (int e = 1; e < 8; ++e) if (a[e] > m) { m = a[e]; am = e; }
      float s = 0.f, ex[8];
      for (int e = 0; e < 8; ++e) { ex[e] = expf(a[e] - m); s += ex[e]; }
      float inv = 1.f / s;
      int am2 = -1; float m2 = -3.4e38f;
      for (int e = 0; e < 8; ++e) if (e != am && a[e] > m2) { m2 = a[e]; am2 = e; }
      float p0 = ex[am] * inv, p1 = ex[am2] * inv;
      float rn = 1.f / (p0 + p1 + 1e-9f);
      e01[t] = make_int2(am, am2);
      p01[t] = make_float2(p0 * rn, p1 * rn);
      tok_row[t] = t;            // shared-group rows: identity gather, weight 1
      scale_row[t] = 1.f;
      atomicAdd(&fc[am], 1);
      for (int e = 0; e < 8; ++e) atomicAdd(&ps[e], ex[e] * inv);
    }
  }
  __syncthreads();
  if (tid < 8) { psum_part[blockIdx.x * 8 + tid] = ps[tid]; fcnt_part[blockIdx.x * 8 + tid] = fc[tid]; }
}

// ------- dispatch (+stat reduce +aux): stable rank within expert, capacity drop -------
__global__ __launch_bounds__(256) void dispatch_kernel(
    const int2* __restrict__ e01, const float2* __restrict__ p01,
    int* __restrict__ tok_row, float* __restrict__ scale_row, int* __restrict__ counts,
    const float* __restrict__ psum_part, const int* __restrict__ fcnt_part,
    float* __restrict__ aux_out) {
  __shared__ int lcnt[256][8];
  __shared__ float wps[4][8];
  __shared__ int wfcs[4][8];
  __shared__ float aps[8];
  __shared__ int afc[8];
  int tid = threadIdx.x, lane = tid & 63, w = tid >> 6;
  float s[8]; int c[8];
#pragma unroll
  for (int e = 0; e < 8; ++e) { s[e] = psum_part[tid * 8 + e]; c[e] = fcnt_part[tid * 8 + e]; }
#pragma unroll
  for (int off = 32; off >= 1; off >>= 1)
#pragma unroll
    for (int e = 0; e < 8; ++e) { s[e] += __shfl_xor(s[e], off); c[e] += __shfl_xor(c[e], off); }
  if (lane == 0) {
#pragma unroll
    for (int e = 0; e < 8; ++e) { wps[w][e] = s[e]; wfcs[w][e] = c[e]; }
  }
  int my[8];
#pragma unroll
  for (int e = 0; e < 8; ++e) my[e] = 0;
  int base = tid * 64;  // 256 threads * 64 entries = 16384 = N*K, contiguous => stable
  for (int j = 0; j < 64; ++j) {
    int ent = base + j; int t = ent >> 1;
    int2 ee = e01[t];
    int ex = (ent & 1) ? ee.y : ee.x;
    my[ex]++;
  }
#pragma unroll
  for (int e = 0; e < 8; ++e) lcnt[tid][e] = my[e];
  __syncthreads();
  if (tid < 8) {
    aps[tid] = wps[0][tid] + wps[1][tid] + wps[2][tid] + wps[3][tid];
    afc[tid] = wfcs[0][tid] + wfcs[1][tid] + wfcs[2][tid] + wfcs[3][tid];
    int run = 0;
    for (int i = 0; i < 256; ++i) { int cc = lcnt[i][tid]; lcnt[i][tid] = run; run += cc; }
    counts[tid] = run < CAP ? run : CAP;
  }
  __syncthreads();
  int offs[8];
#pragma unroll
  for (int e = 0; e < 8; ++e) offs[e] = lcnt[tid][e];
  for (int j = 0; j < 64; ++j) {
    int ent = base + j; int t = ent >> 1; int k = ent & 1;
    int2 ee = e01[t];
    int ex = k ? ee.y : ee.x;
    float pr = k ? p01[t].y : p01[t].x;
    int pos = offs[ex]++;
    if (pos < CAP) {
      int row = NTOK + ex * CAP + pos;
      tok_row[row] = t;
      scale_row[row] = pr;
    }
  }
  if (tid == 0) {
    float t = 0.f;
    for (int e = 0; e < 8; ++e) t += ((float)afc[e] / 8192.f) * (aps[e] / 8192.f);
    *aux_out = 0.08f * t;  // AUX_COEF * E = 0.01 * 8
  }
}

// ---------------- grouped GEMM, 128x128 tile, BK=64, 4 waves, single-buffer (m97 structure) ----------------
// R8/R10/R13/R15/R16-verified. XOR chunk-swizzle, XCD remap, 4 blocks/CU.
// RANGE: 0 = shared+expert tiles (GEMM1), 2 = expert-only (GEMM2b).
// EPI: 1 = H-store bf16(relu^2); 2 = atomicAdd(y, v*scale).
template <int KD, int NDT, bool GATHER, int EPI, int RANGE>
__global__ __launch_bounds__(256, 4) void gemm_kernel(
    const __bf16* __restrict__ A, const __bf16* __restrict__ B,
    __bf16* __restrict__ Hout, float* __restrict__ Yout,
    const int* __restrict__ counts, const int* __restrict__ tok_row,
    const float* __restrict__ scale_row) {
  constexpr int NCT = NDT / 128;
  constexpr int SH = NTOK / 128;   // 64 shared row-tiles
  constexpr int ET = CAP / 128;    // 20 expert row-tiles (worst case)
  int nwg = gridDim.x;
  int lin = (blockIdx.x & 7) * (nwg >> 3) + (blockIdx.x >> 3);
  int rem = lin % (4 * NCT);
  int rt = (lin / (4 * NCT)) * 4 + (rem & 3);
  int ct = rem >> 2;

  int g, i0, rowbase;
  if (RANGE == 2) { g = rt / ET; i0 = (rt % ET) << 7; rowbase = NTOK + g * CAP; }
  else {
    if (rt < SH) { g = 8; rowbase = 0; i0 = rt << 7; }
    else { int r = rt - SH; g = r / ET; i0 = (r % ET) << 7; rowbase = NTOK + g * CAP; }
  }
  int cnt = (g == 8) ? NTOK : counts[g];
  if (i0 >= cnt) return;  // uniform early-exit

  __shared__ __align__(16) __bf16 As[128 * 64];   // 16 KB
  __shared__ __align__(16) __bf16 Bs[128 * 64];   // 16 KB
  __shared__ int   toksL[128];
  __shared__ float sclL[128];

  int tid = threadIdx.x, lane = tid & 63, wid = tid >> 6;

  if (tid < 128) {
    int i = i0 + tid; if (i > cnt - 1) i = cnt - 1;  // pad rows duplicate last valid
    toksL[tid] = tok_row[rowbase + i];
    if (EPI == 2) sclL[tid] = scale_row[rowbase + i];
  }
  __syncthreads();

  int rsub = lane >> 3, csub = lane & 7;
  int csw = (csub ^ rsub) * 16;
  const char* aP[4];
  const char* bP[4];
  const char* Bg = (const char*)B + (size_t)g * NDT * KD * 2;
#pragma unroll
  for (int t = 0; t < 4; ++t) {
    int ia = wid * 32 + t * 8 + rsub;
    size_t arow = GATHER ? (size_t)toksL[ia] : (size_t)(rowbase + i0 + ia);
    aP[t] = (const char*)A + arow * (size_t)(KD * 2) + csw;
    int ib = ct * 128 + wid * 32 + t * 8 + rsub;
    bP[t] = Bg + (size_t)ib * (KD * 2) + csw;
  }

  f32x4 acc[4][4];
#pragma unroll
  for (int m2 = 0; m2 < 4; ++m2)
#pragma unroll
    for (int n2 = 0; n2 < 4; ++n2) acc[m2][n2] = f32x4{0.f, 0.f, 0.f, 0.f};

  int wr = wid >> 1, wc = wid & 1;
  int rA[4], rB[4], cS[2];
#pragma unroll
  for (int m2 = 0; m2 < 4; ++m2) rA[m2] = (wr * 64 + m2 * 16 + (lane & 15)) * 64;
#pragma unroll
  for (int n2 = 0; n2 < 4; ++n2) rB[n2] = (wc * 64 + n2 * 16 + (lane & 15)) * 64;
#pragma unroll
  for (int kk = 0; kk < 2; ++kk) cS[kk] = ((kk * 4 + (lane >> 4)) ^ (lane & 7)) * 8;

  for (int k0 = 0; k0 < KD; k0 += 64) {
    size_t kb = (size_t)k0 * 2;
#pragma unroll
    for (int t = 0; t < 4; ++t) {
      load_lds16(aP[t] + kb, &As[(wid * 32 + t * 8) * 64]);
      load_lds16(bP[t] + kb, &Bs[(wid * 32 + t * 8) * 64]);
    }
    __syncthreads();
#pragma unroll
    for (int kk = 0; kk < 2; ++kk) {
      bf16x8 af[4], bfr[4];
#pragma unroll
      for (int m2 = 0; m2 < 4; ++m2) af[m2] = *(const bf16x8*)&As[rA[m2] + cS[kk]];
#pragma unroll
      for (int n2 = 0; n2 < 4; ++n2) bfr[n2] = *(const bf16x8*)&Bs[rB[n2] + cS[kk]];
#pragma unroll
      for (int m2 = 0; m2 < 4; ++m2)
#pragma unroll
        for (int n2 = 0; n2 < 4; ++n2)
          acc[m2][n2] = __builtin_amdgcn_mfma_f32_16x16x32_bf16(af[m2], bfr[n2], acc[m2][n2], 0, 0, 0);
    }
    __syncthreads();
  }

  // epilogue; C/D frag: col = lane&15, row = (lane>>4)*4 + reg  [verified m89/m91]
#pragma unroll
  for (int m2 = 0; m2 < 4; ++m2) {
    int rb = wr * 64 + m2 * 16 + ((lane >> 4) << 2);
#pragma unroll
    for (int n2 = 0; n2 < 4; ++n2) {
      int col = ct * 128 + wc * 64 + n2 * 16 + (lane & 15);
#pragma unroll
      for (int r = 0; r < 4; ++r) {
        int grow = i0 + rb + r;
        if (grow < cnt) {
          float v = acc[m2][n2][r];
          if constexpr (EPI == 1) {
            v = fmaxf(v, 0.f);
            Hout[(size_t)(rowbase + grow) * NDT + col] = (__bf16)(v * v);
          } else {
            atomicAdd(&Yout[(size_t)toksL[rb + r] * NDT + col], v * sclL[rb + r]);
          }
        }
      }
    }
  }
}

// ---------------- GEMM2a (shared -> y plain store), 64x128 tile, 4 waves, 4 blocks/CU ----------------
// Same m97 loop/swizzle family; tile shrunk to 64 rows so the shared-only
// grid becomes 128rt x 8ct = 1024 blocks = 4 blocks/CU (was 512 = 2/CU).
// Waves 1M x 4N: wave-tile 64x32, acc[4][2] (~92 VGPR < 128 cap). Identity
// rows, weight 1: y[row][col] = v (plain store replaces zeroing).
__global__ __launch_bounds__(256, 4) void gemm2s_kernel(
    const __bf16* __restrict__ A, const __bf16* __restrict__ B,
    float* __restrict__ Yout) {
  constexpr int KD = HDIM;         // 1408
  // XCD remap: nwg=1024, 4-rt chunks, NCT=8 -> lin%32
  int nwg = gridDim.x;
  int lin = (blockIdx.x & 7) * (nwg >> 3) + (blockIdx.x >> 3);
  int rem = lin % 32;
  int rt = (lin / 32) * 4 + (rem & 3);   // 0..127
  int ct = rem >> 2;                     // 0..7
  int i0 = rt << 6;                      // 64 rows per tile

  __shared__ __align__(16) __bf16 As[64 * 64];    // 8 KB
  __shared__ __align__(16) __bf16 Bs[128 * 64];   // 16 KB

  int tid = threadIdx.x, lane = tid & 63, wid = tid >> 6;

  // staging: A 8 instrs (64 rows), B 16 instrs (128 rows); per wave 2 A + 4 B.
  // instr covers 8 rows x 128B; lane -> row j*8+(lane>>3), chunk lane&7,
  // source chunk XOR (row&7) = (lane>>3).
  int rsub = lane >> 3, csub = lane & 7;
  int csw = (csub ^ rsub) * 16;
  const char* gA[2];
  const char* gB[4];
  const char* Bg = (const char*)B + (size_t)8 * DDIM * KD * 2;   // shared B2 slice
#pragma unroll
  for (int q = 0; q < 2; ++q) {
    int row = (wid * 2 + q) * 8 + rsub;                 // 0..63
    gA[q] = (const char*)A + (size_t)(i0 + row) * (KD * 2) + csw;
  }
#pragma unroll
  for (int q = 0; q < 4; ++q) {
    int row = (wid * 4 + q) * 8 + rsub;                 // 0..127
    gB[q] = Bg + (size_t)(ct * 128 + row) * (KD * 2) + csw;
  }

  f32x4 acc[4][2];
#pragma unroll
  for (int m2 = 0; m2 < 4; ++m2)
#pragma unroll
    for (int n2 = 0; n2 < 2; ++n2) acc[m2][n2] = f32x4{0.f, 0.f, 0.f, 0.f};

  // wave-tile 64x32 at col wid*32; read offsets (elements), swizzle matches
  int rA[4], rB[2], cS[2];
#pragma unroll
  for (int m2 = 0; m2 < 4; ++m2) rA[m2] = (m2 * 16 + (lane & 15)) * 64;
#pragma unroll
  for (int n2 = 0; n2 < 2; ++n2) rB[n2] = (wid * 32 + n2 * 16 + (lane & 15)) * 64;
#pragma unroll
  for (int kk = 0; kk < 2; ++kk) cS[kk] = ((kk * 4 + (lane >> 4)) ^ (lane & 7)) * 8;

  for (int k0 = 0; k0 < KD; k0 += 64) {
    size_t kb = (size_t)k0 * 2;
#pragma unroll
    for (int q = 0; q < 2; ++q)
      load_lds16(gA[q] + kb, &As[((wid * 2 + q) * 8) * 64]);
#pragma unroll
    for (int q = 0; q < 4; ++q)
      load_lds16(gB[q] + kb, &Bs[((wid * 4 + q) * 8) * 64]);
    __syncthreads();
#pragma unroll
    for (int kk = 0; kk < 2; ++kk) {
      bf16x8 af[4], bfr[2];
#pragma unroll
      for (int m2 = 0; m2 < 4; ++m2) af[m2] = *(const bf16x8*)&As[rA[m2] + cS[kk]];
#pragma unroll
      for (int n2 = 0; n2 < 2; ++n2) bfr[n2] = *(const bf16x8*)&Bs[rB[n2] + cS[kk]];
#pragma unroll
      for (int m2 = 0; m2 < 4; ++m2)
#pragma unroll
        for (int n2 = 0; n2 < 2; ++n2)
          acc[m2][n2] = __builtin_amdgcn_mfma_f32_16x16x32_bf16(af[m2], bfr[n2], acc[m2][n2], 0, 0, 0);
    }
    __syncthreads();
  }

  // epilogue: plain store (identity rows, weight 1); col = ct*128 + wid*32 + ...
#pragma unroll
  for (int m2 = 0; m2 < 4; ++m2) {
    int rb = m2 * 16 + ((lane >> 4) << 2);
#pragma unroll
    for (int n2 = 0; n2 < 2; ++n2) {
      int col = ct * 128 + wid * 32 + n2 * 16 + (lane & 15);
#pragma unroll
      for (int r = 0; r < 4; ++r)
        Yout[(size_t)(i0 + rb + r) * DDIM + col] = acc[m2][n2][r];
    }
  }
}

extern "C" void kernel_launch(void* const* d_in, const int* in_sizes, int n_in,
                              void* d_out, int out_size, void* d_ws, size_t ws_size,
                              hipStream_t stream) {
  const float* x      = (const float*)d_in[0];
  const float* rw     = (const float*)d_in[1];
  const float* wfc    = (const float*)d_in[2];
  const float* wproj  = (const float*)d_in[3];
  const float* wsfc   = (const float*)d_in[4];
  const float* wsproj = (const float*)d_in[5];
  float* y = (float*)d_out;

  char* ws = (char*)d_ws;
  size_t off = 0;
  auto alloc = [&](size_t bytes) {
    void* p = ws + off;
    off += (bytes + 1023) & ~(size_t)1023;
    return p;
  };
  __bf16* xbf      = (__bf16*)alloc((size_t)NTOK * DDIM * 2);          // 16 MB
  __bf16* B1       = (__bf16*)alloc((size_t)9 * HDIM * DDIM * 2);      // 26 MB [9][1408][1024]
  __bf16* B2       = (__bf16*)alloc((size_t)9 * DDIM * HDIM * 2);      // 26 MB [9][1024][1408]
  __bf16* H        = (__bf16*)alloc((size_t)NROWS * HDIM * 2);         // 81 MB
  int*    tok_row  = (int*)alloc((size_t)NROWS * 4);
  float*  scale_row= (float*)alloc((size_t)NROWS * 4);
  int2*   e01      = (int2*)alloc((size_t)NTOK * 8);
  float2* p01      = (float2*)alloc((size_t)NTOK * 8);
  int*    counts   = (int*)alloc(1024);
  float*  psum_part= (float*)alloc(256 * 8 * 4);
  int*    fcnt_part= (int*)alloc(256 * 8 * 4);
  (void)ws_size; (void)out_size; (void)in_sizes; (void)n_in;

  tconv3_kernel<<<dim3(44, 22, 18), 256, 0, stream>>>(wfc, B1, wsfc, wproj, B2, wsproj);
  router_kernel<<<256, 256, 0, stream>>>(x, rw, xbf, e01, p01, tok_row, scale_row,
                                         psum_part, fcnt_part);
  dispatch_kernel<<<1, 256, 0, stream>>>(e01, p01, tok_row, scale_row, counts,
                                         psum_part, fcnt_part, y + YN);
  // GEMM1: H = relu(gather(x) @ B1)^2 ; 128x128 tiles: (64 + 8*20) rt * 11 ct = 2464
  gemm_kernel<1024, 1408, true, 1, 0><<<2464, 256, 0, stream>>>(
      xbf, B1, H, nullptr, counts, tok_row, scale_row);
  // GEMM2a (shared): y = H_shared @ B2s (plain store; 64x128 tiles, 1024 blocks = 4/CU)
  gemm2s_kernel<<<1024, 256, 0, stream>>>(H, B2, y);
  // GEMM2b (experts): y += scale * (H_exp @ B2)  (atomicAdd on top)
  gemm_kernel<1408, 1024, false, 2, 2><<<1280, 256, 0, stream>>>(
      H, B2, nullptr, y, counts, tok_row, scale_row);
}